// Round 3
// baseline (246.534 us; speedup 1.0000x reference)
//
#include <hip/hip_runtime.h>
#include <stdint.h>

typedef unsigned int u32;
typedef unsigned long long u64;

#define N8   130560   // (2176/8)*(3840/8)   = 272*480
#define N16  32640    // (2176/16)*(3840/16) = 136*240
#define N32  8160     // (2176/32)*(3840/32) = 68*120
#define NTOT 171360
#define NTOT4 42840   // NTOT/4
#define TOPK 1000
#define NWORDS 16
#define NBINS 4096
#define BUCKET_SCALE 682.0f
#define LIST_CAP 2048
#define OUT_ELEMS 15000
#define IOU_TASKS (TOPK * NWORDS)
#define IOU_BLOCKS ((IOU_TASKS + 255) / 256)   // 63

// workspace layout (bytes)
#define OFF_HIST   0        // u32[4096]
#define OFF_META   16384    // u32[16]: 0=B 1=listCnt 2=histBlkCtr 3=iouBlkCtr
#define OFF_NZ     16448    // u64[16]
#define OFF_VALID  16576    // u64[16]
#define MEMSET_BYTES 16704  // hist+meta+nz+valid (everything below is fully overwritten)
#define OFF_BOXES  16704    // f32[4000] (16B aligned)
#define OFF_SCORES 32704    // f32[1000]
#define OFF_KPS    36704    // f32[10000]
#define OFF_LIST   76704    // u64[2048]
#define OFF_MASK   93088    // u64[1000*16]

__device__ __forceinline__ u32 bucket_of(float x) {
  u32 b = (u32)(x * BUCKET_SCALE);
  return b > (NBINS - 1) ? (NBINS - 1) : b;
}

__device__ __forceinline__ float4 load_logit4(int v, const float* s8, const float* s16,
                                              const float* s32) {
  int e = v * 4;
  if (e < N8) return ((const float4*)s8)[v];
  if (e < N8 + N16) return ((const float4*)s16)[v - N8 / 4];
  return ((const float4*)s32)[v - (N8 + N16) / 4];
}

// K1: histogram of positive logits (float4 loads) + fused findB in the last block.
__global__ void k_hist_findB(const float* __restrict__ s8, const float* __restrict__ s16,
                             const float* __restrict__ s32, u32* __restrict__ hist,
                             u32* __restrict__ meta) {
  int v = blockIdx.x * 256 + threadIdx.x;
  if (v < NTOT4) {
    float4 x = load_logit4(v, s8, s16, s32);
    if (x.x > 0.0f) atomicAdd(&hist[bucket_of(x.x)], 1u);
    if (x.y > 0.0f) atomicAdd(&hist[bucket_of(x.y)], 1u);
    if (x.z > 0.0f) atomicAdd(&hist[bucket_of(x.z)], 1u);
    if (x.w > 0.0f) atomicAdd(&hist[bucket_of(x.w)], 1u);
  }
  __threadfence();
  __shared__ int isLast;
  if (threadIdx.x == 0)
    isLast = (atomicAdd(&meta[2], 1u) == gridDim.x - 1) ? 1 : 0;
  __syncthreads();
  if (!isLast) return;

  __shared__ u32 hloc[NBINS];
  __shared__ u32 csum[256];
  int t = threadIdx.x;
  u32 sum = 0;
  for (int k = 0; k < 16; ++k) {
    u32 val = atomicAdd(&hist[t * 16 + k], 0u);   // device-coherent read
    hloc[t * 16 + k] = val;
    sum += val;
  }
  csum[t] = sum;
  __syncthreads();
  if (t == 0) {
    u32 cum = 0, B = 0;
    for (int ct = 255; ct >= 0; --ct) {
      if (cum + csum[ct] >= TOPK) {
        for (int b = ct * 16 + 15; b >= ct * 16; --b) {
          cum += hloc[b];
          if (cum >= TOPK) { B = (u32)b; break; }
        }
        break;
      }
      cum += csum[ct];
    }
    meta[0] = B;
  }
}

// K2: compact candidates with bucket >= B into list as (logit_bits<<32)|~idx
__global__ void k_compact(const float* __restrict__ s8, const float* __restrict__ s16,
                          const float* __restrict__ s32,
                          u32* __restrict__ meta, u64* __restrict__ list) {
  int v = blockIdx.x * 256 + threadIdx.x;
  if (v >= NTOT4) return;
  float4 x = load_logit4(v, s8, s16, s32);
  u32 B = meta[0];
  float c[4] = {x.x, x.y, x.z, x.w};
#pragma unroll
  for (int j = 0; j < 4; ++j) {
    float xx = c[j];
    if (xx > 0.0f && bucket_of(xx) >= B) {
      u32 pos = atomicAdd(&meta[1], 1u);
      if (pos < LIST_CAP) {
        u32 idx = (u32)(v * 4 + j);
        list[pos] = ((u64)__float_as_uint(xx) << 32) | (u64)(~idx);
      }
    }
  }
}

// K3: O(n^2) exact rank (descending key = stable top-k order) + decode, scattered to rank.
// 8 blocks x 256 = 2048 threads, one candidate each. Rows [cnt,1000) zeroed here.
__global__ void k_rank_decode(
    const u64* __restrict__ list, const u32* __restrict__ meta,
    const float* __restrict__ bb8,  const float* __restrict__ kp8,
    const float* __restrict__ bb16, const float* __restrict__ kp16,
    const float* __restrict__ bb32, const float* __restrict__ kp32,
    float* __restrict__ sBoxes, float* __restrict__ sScores,
    float* __restrict__ sKps, u64* __restrict__ validWords) {
  __shared__ u64 keys[LIST_CAP];
  int t = threadIdx.x;
  u32 cnt = meta[1];                 // prev-dispatch write: plain load is coherent
  if (cnt > LIST_CAP) cnt = LIST_CAP;
  int tid = blockIdx.x * 256 + t;
  for (int j = t; j < LIST_CAP; j += 256) keys[j] = (j < (int)cnt) ? list[j] : 0ull;
  __syncthreads();

  if (tid < (int)cnt) {
    u64 my = keys[tid];
    int rank = 0;
    int j = 0;
    for (; j + 4 <= (int)cnt; j += 4) {
      rank += (keys[j] > my) + (keys[j + 1] > my) + (keys[j + 2] > my) + (keys[j + 3] > my);
    }
    for (; j < (int)cnt; ++j) rank += (keys[j] > my);
    if (rank < TOPK) {
      u64 key = my;
      float x = __uint_as_float((u32)(key >> 32));
      float sc = (float)(1.0 / (1.0 + exp(-(double)x)));   // sigmoid in f64, round once
      u32 idx = ~((u32)key);
      float4 box;
      float kv[10];
      int p, xq, yq;
      float st;
      const float *bb, *kp;
      if (idx < N8) {
        st = 8.f;  p = (int)idx;              xq = p % 480; yq = p / 480; bb = bb8;  kp = kp8;
      } else if (idx < N8 + N16) {
        st = 16.f; p = (int)idx - N8;         xq = p % 240; yq = p / 240; bb = bb16; kp = kp16;
      } else {
        st = 32.f; p = (int)idx - (N8 + N16); xq = p % 120; yq = p / 120; bb = bb32; kp = kp32;
      }
      float cx = (float)xq * st, cy = (float)yq * st;
      {
#pragma clang fp contract(off)
        float d0 = bb[4 * p + 0] * st;
        float d1 = bb[4 * p + 1] * st;
        float d2 = bb[4 * p + 2] * st;
        float d3 = bb[4 * p + 3] * st;
        box.x = cx - d0; box.y = cy - d1; box.z = cx + d2; box.w = cy + d3;
        for (int q = 0; q < 10; ++q)
          kv[q] = kp[10 * p + q] * st + ((q & 1) ? cy : cx);
      }
      ((float4*)sBoxes)[rank] = box;
      sScores[rank] = sc;
      for (int q = 0; q < 10; ++q) sKps[10 * rank + q] = kv[q];
      atomicOr(&validWords[rank >> 6], 1ull << (rank & 63));
    }
  } else if (tid < TOPK) {
    // unfilled rows (cnt <= tid < 1000): zero them (validWords stays 0 from memset)
    ((float4*)sBoxes)[tid] = make_float4(0.f, 0.f, 0.f, 0.f);
    sScores[tid] = 0.f;
    for (int q = 0; q < 10; ++q) sKps[10 * tid + q] = 0.f;
  }
}

__device__ __forceinline__ bool iou_gt04(float4 a, float4 b) {
#pragma clang fp contract(off)
  float areaA = (a.z - a.x) * (a.w - a.y);
  float areaB = (b.z - b.x) * (b.w - b.y);
  float ltx = fmaxf(a.x, b.x);
  float lty = fmaxf(a.y, b.y);
  float rbx = fminf(a.z, b.z);
  float rby = fminf(a.w, b.w);
  float wx = rbx - ltx; wx = wx > 0.0f ? wx : 0.0f;
  float wy = rby - lty; wy = wy > 0.0f ? wy : 0.0f;
  float inter = wx * wy;
  float un = areaA + areaB - inter;
  un = un > 1e-9f ? un : 1e-9f;
  return (inter / un) > 0.4f;
}

// K4: suppression bitmask + nz bitmap; last block runs exact greedy NMS (1 wave over
// nonzero-mask rows only — rows with empty suppression sets can't change the removed
// set, so skipping them is exact) and then finalizes the output.
__global__ void k_iou_nms_fin(const float* __restrict__ sBoxes, const float* __restrict__ sScores,
                              const float* __restrict__ sKps, const u64* __restrict__ validWords,
                              u64* mask, u64* nzWords, u32* meta, float* __restrict__ out) {
  __shared__ float4 boxes[TOPK];
  int t = threadIdx.x;
  for (int r = t; r < TOPK; r += 256) boxes[r] = ((const float4*)sBoxes)[r];
  __syncthreads();
  int task = blockIdx.x * 256 + t;
  if (task < IOU_TASKS) {
    int i = task >> 4, w = task & 15;
    float4 a = boxes[i];
    u64 bits = 0;
    int base = w * 64;
    int j0 = base > (i + 1) ? base : (i + 1);
    int j1 = (base + 64) < TOPK ? (base + 64) : TOPK;
    for (int j = j0; j < j1; ++j) {
      if (iou_gt04(a, boxes[j])) bits |= 1ull << (j - base);
    }
    mask[(u64)i * NWORDS + w] = bits;
    if (bits) atomicOr(&nzWords[i >> 6], 1ull << (i & 63));
  }
  __threadfence();
  __shared__ int isLast;
  if (t == 0)
    isLast = (atomicAdd(&meta[3], 1u) == gridDim.x - 1) ? 1 : 0;
  __syncthreads();
  if (!isLast) return;

  // ---- last block: greedy NMS (wave 0) ----
  __shared__ u64 keepL[NWORDS];
  if (t < 64) {
    u64 vw  = (t < NWORDS) ? validWords[t] : 0ull;                 // prev-kernel data
    u64 nzw = (t < NWORDS) ? atomicOr(&nzWords[t], 0ull) : 0ull;   // same-kernel: atomic read
    u64 remv = 0;
    for (int c = 0; c < NWORDS; ++c) {
      u64 nzc = __shfl(nzw, c) & __shfl(vw, c);   // wave-uniform candidate suppressors
      while (nzc) {
        int b = __builtin_ctzll(nzc);
        nzc &= nzc - 1;
        u64 remc = __shfl(remv, c);
        if (!((remc >> b) & 1ull)) {              // row still alive -> apply its row
          int i = c * 64 + b;
          u64 m = (t < NWORDS) ? atomicOr(&mask[(u64)i * NWORDS + t], 0ull) : 0ull;
          remv |= m;
        }
      }
    }
    if (t < NWORDS) keepL[t] = vw & ~remv;
  }
  __syncthreads();

  // ---- finalize: [boxes 4000 | scores 1000 | kps 10000] ----
  for (int o = t; o < OUT_ELEMS; o += 256) {
    int row; float v;
    if (o < 4000)      { row = o >> 2;   v = sBoxes[o]; }
    else if (o < 5000) { row = o - 4000; v = sScores[row]; }
    else               { int q = o - 5000; row = q / 10; v = sKps[q]; }
    u64 kw = keepL[row >> 6];
    out[o] = ((kw >> (row & 63)) & 1ull) ? v : 0.0f;
  }
}

extern "C" void kernel_launch(void* const* d_in, const int* in_sizes, int n_in,
                              void* d_out, int out_size, void* d_ws, size_t ws_size,
                              hipStream_t stream) {
  const float* s8   = (const float*)d_in[1];
  const float* bb8  = (const float*)d_in[2];
  const float* kp8  = (const float*)d_in[3];
  const float* s16  = (const float*)d_in[4];
  const float* bb16 = (const float*)d_in[5];
  const float* kp16 = (const float*)d_in[6];
  const float* s32  = (const float*)d_in[7];
  const float* bb32 = (const float*)d_in[8];
  const float* kp32 = (const float*)d_in[9];

  char* ws = (char*)d_ws;
  u32* hist       = (u32*)(ws + OFF_HIST);
  u32* meta       = (u32*)(ws + OFF_META);
  u64* nzWords    = (u64*)(ws + OFF_NZ);
  u64* validWords = (u64*)(ws + OFF_VALID);
  float* sBoxes   = (float*)(ws + OFF_BOXES);
  float* sScores  = (float*)(ws + OFF_SCORES);
  float* sKps     = (float*)(ws + OFF_KPS);
  u64* list       = (u64*)(ws + OFF_LIST);
  u64* mask       = (u64*)(ws + OFF_MASK);

  hipMemsetAsync(ws, 0, MEMSET_BYTES, stream);

  int nbv = (NTOT4 + 255) / 256;  // 168
  k_hist_findB<<<nbv, 256, 0, stream>>>(s8, s16, s32, hist, meta);
  k_compact<<<nbv, 256, 0, stream>>>(s8, s16, s32, meta, list);
  k_rank_decode<<<8, 256, 0, stream>>>(list, meta, bb8, kp8, bb16, kp16, bb32, kp32,
                                       sBoxes, sScores, sKps, validWords);
  k_iou_nms_fin<<<IOU_BLOCKS, 256, 0, stream>>>(sBoxes, sScores, sKps, validWords,
                                                mask, nzWords, meta, (float*)d_out);
}